// Round 5
// baseline (521.818 us; speedup 1.0000x reference)
//
#include <hip/hip_runtime.h>
#include <math.h>

// MemoryUnit: fn=l2norm(feature), mn=l2norm(memory), S=fn.mn^T -> softmax ->
// hardshrink(0.0005) -> softmax -> w ; mem_feat = w @ memory.
// Round 10: Mem16 side-write (L3 play).
//  Evidence: r3 schedule-null + r4 Spart-bf16 delta matching the L3 model
//  (-3.9us ~= 100MB @ 25TB/s) => kernels are BW-floor-bound and intermediates
//  are L3-served. Last controllable HBM item: memory fetched twice (2x262MB).
//  - gemm1 already converts memory fp32->bf16 in regs; now it ALSO stores the
//    converted tile to Mem16 (131 MB, fits L3). Worst case (no L3 retention)
//    131w+131r == 262r (neutral); best case gemm2 reads Mem16 from L3.
//  - gemm2 reads Mem16 (bf16, no conversion) instead of fp32 memory.
//    Bit-identical numerics: same f2bf applied to the same values, just one
//    kernel earlier.
//  - zero_kernel folded into prep_feat (one fewer dispatch).
//  - Everything else identical to the round-4 verified kernel.

#define D_DIM 32768
#define B_DIM 256
#define M_DIM 2000
#define M_PAD 2048
#define NS1 16
#define KSLAB (D_DIM / NS1)   // 2048
#define LAM 0.0005f
#define LDB 72                // padded LDS stride (ushorts) for gemm1 B tile

typedef __attribute__((ext_vector_type(8))) short bf16x8;   // 8 bf16 = 4 VGPR
typedef __attribute__((ext_vector_type(4))) float f32x4;

#define GLOBAL_AS __attribute__((address_space(1)))
#define LDS_AS __attribute__((address_space(3)))

__device__ __forceinline__ void cp_async16(const void* g, void* l) {
  // 64 lanes x 16B -> LDS base + lane*16 (wave-uniform lds base required)
  __builtin_amdgcn_global_load_lds((const GLOBAL_AS unsigned int*)g,
                                   (LDS_AS unsigned int*)l, 16, 0, 0);
}

__device__ __forceinline__ unsigned short f2bf(float f) {
  union { float f; unsigned u; } v; v.f = f;
  unsigned r = v.u + 0x7FFFu + ((v.u >> 16) & 1u);  // RNE
  return (unsigned short)(r >> 16);
}

__device__ __forceinline__ float bf2f(unsigned short h) {
  union { unsigned u; float f; } v; v.u = ((unsigned)h) << 16;
  return v.f;
}

// ---------------- prep feature: fp32 -> bf16 + 1/max(||x||,eps) + rnm_sq zero ----
__global__ __launch_bounds__(256) void prep_feat_kernel(const float* __restrict__ src,
                                                        unsigned short* __restrict__ dst,
                                                        float* __restrict__ rn_inv,
                                                        float* __restrict__ rnm_sq) {
  const size_t row = blockIdx.x;
  const int t = threadIdx.x;
  // folded zero_kernel: 256 blocks x 8 = 2048 entries (stream order guarantees
  // completion before gemm1's atomics)
  if (t < 8) rnm_sq[(blockIdx.x << 3) + t] = 0.f;
  const float4* p = (const float4*)(src + row * (size_t)D_DIM);
  ushort4* q = (ushort4*)(dst + row * (size_t)D_DIM);
  float s = 0.f;
  for (int i = t; i < D_DIM / 4; i += 256) {
    float4 v = p[i];
    s = fmaf(v.x, v.x, s); s = fmaf(v.y, v.y, s);
    s = fmaf(v.z, v.z, s); s = fmaf(v.w, v.w, s);
    ushort4 b; b.x = f2bf(v.x); b.y = f2bf(v.y); b.z = f2bf(v.z); b.w = f2bf(v.w);
    q[i] = b;
  }
  #pragma unroll
  for (int off = 32; off > 0; off >>= 1) s += __shfl_down(s, off, 64);
  __shared__ float partial[4];
  if ((t & 63) == 0) partial[t >> 6] = s;
  __syncthreads();
  if (t == 0) {
    float tt = partial[0] + partial[1] + partial[2] + partial[3];
    rn_inv[row] = 1.0f / fmaxf(sqrtf(tt), 1e-12f);
  }
}

// ---------------- fused GEMM1 + memory norm + Mem16 side-write ----------------
// 1-D grid 512, XCD-decoded: xcd=bid&7, slot=bid>>3; split=xcd*2+(slot>=32),
// mtile=slot&31. A = F16 (cp_async16, swizzled unpadded LDS, double-buffered);
// B = memory fp32 prefetched to regs -> cvt bf16 -> padded LDS + Mem16 global
// store (side-product, exact values gemm2 needs); sumsq accumulated. Spart
// written bf16. All barriers full __syncthreads().
__global__ __launch_bounds__(256, 2) void gemm1_fused(const unsigned short* __restrict__ F16,
                                                      const float* __restrict__ mem,
                                                      unsigned short* __restrict__ Spart,
                                                      float* __restrict__ rnm_sq,
                                                      unsigned short* __restrict__ Mem16) {
  __shared__ __align__(16) unsigned short Asm[2][256 * 64];   // 64 KB dbuf, swizzled
  __shared__ __align__(16) unsigned short Bsm[64 * LDB];      // 9 KB, padded
  const int t = threadIdx.x;
  const int bid = blockIdx.x;
  const int xcd = bid & 7, slot = bid >> 3;
  const int ysplit = xcd * 2 + (slot >> 5);   // 0..15
  const int m0 = (slot & 31) * 64;
  const int kbase = ysplit * KSLAB;
  const int wid = t >> 6, lane = t & 63;
  const int lr = lane & 15, kq = lane >> 4;
  const int l8 = lane & 7, lrow = lane >> 3;

  // B staging: thread handles row (t>>2), 16 floats at col (t&3)*16
  const int brow = t >> 2;
  const int bcol = (t & 3) * 16;
  const int gm = m0 + brow;
  const bool bvalid = gm < M_DIM;
  // OOB rows clamped to row 0: products land in S columns >= M_DIM (masked in
  // softmax); ss and Mem16 store are guarded by bvalid.
  const float* Bg = mem + (size_t)(bvalid ? gm : 0) * D_DIM + kbase + bcol;
  unsigned short* M16b = Mem16 + (size_t)gm * D_DIM + kbase + bcol;

  const unsigned short* Ab = F16 + (size_t)(64 * wid + lrow) * D_DIM + kbase + (l8 ^ lrow) * 8;

  f32x4 acc[4][4] = {};
  float ss = 0.f;

  // prologue: stage tile 0
  #pragma unroll
  for (int i = 0; i < 8; i++)
    cp_async16(Ab + (size_t)(8 * i) * D_DIM, &Asm[0][(64 * wid + 8 * i) * 64]);
  float4 v[4];
  #pragma unroll
  for (int j = 0; j < 4; j++) v[j] = *(const float4*)(Bg + 4 * j);

  int cur = 0;
  const int NT = KSLAB / 64;          // 32
  for (int kt = 0; kt < NT; kt++) {
    // phase 1: convert current B regs -> Bsm + Mem16 (+ sumsq)
    unsigned short* M16w = M16b + kt * 64;
    #pragma unroll
    for (int j = 0; j < 4; j++) {
      ss = fmaf(v[j].x, v[j].x, ss); ss = fmaf(v[j].y, v[j].y, ss);
      ss = fmaf(v[j].z, v[j].z, ss); ss = fmaf(v[j].w, v[j].w, ss);
      ushort4 c; c.x = f2bf(v[j].x); c.y = f2bf(v[j].y);
      c.z = f2bf(v[j].z); c.w = f2bf(v[j].w);
      *(ushort4*)&Bsm[brow * LDB + bcol + 4 * j] = c;
      if (bvalid) *(ushort4*)&M16w[4 * j] = c;   // side-write for gemm2
    }
    __syncthreads();   // mid: Bsm visible; Asm[cur] complete (vmcnt drained)

    // phase 2a: issue next-tile prefetch (drains at END-of-iter barrier,
    // hidden under the ds_read+MFMA phase below)
    float4 vn[4];
    if (kt + 1 < NT) {
      const int kk = (kt + 1) * 64;
      #pragma unroll
      for (int i = 0; i < 8; i++)
        cp_async16(Ab + kk + (size_t)(8 * i) * D_DIM, &Asm[cur ^ 1][(64 * wid + 8 * i) * 64]);
      #pragma unroll
      for (int j = 0; j < 4; j++) vn[j] = *(const float4*)(Bg + kk + 4 * j);
    }

    // phase 2b: compute from Asm[cur], Bsm
    bf16x8 bfr[2][4];
    #pragma unroll
    for (int h = 0; h < 2; h++)
      #pragma unroll
      for (int ni = 0; ni < 4; ni++)
        bfr[h][ni] = *(const bf16x8*)&Bsm[(ni * 16 + lr) * LDB + h * 32 + kq * 8];
    #pragma unroll
    for (int mi = 0; mi < 4; mi++) {
      #pragma unroll
      for (int h = 0; h < 2; h++) {
        const int sw = ((h * 4 + kq) ^ (lr & 7)) * 8;
        const bf16x8 af = *(const bf16x8*)&Asm[cur][(wid * 64 + mi * 16 + lr) * 64 + sw];
        #pragma unroll
        for (int ni = 0; ni < 4; ni++)
          acc[mi][ni] = __builtin_amdgcn_mfma_f32_16x16x32_bf16(af, bfr[h][ni], acc[mi][ni], 0, 0, 0);
      }
    }
    __syncthreads();   // end: prefetch drained (hidden under compute)
    if (kt + 1 < NT) {
      #pragma unroll
      for (int j = 0; j < 4; j++) v[j] = vn[j];
    }
    cur ^= 1;
  }

  // sumsq: 4 threads share a row
  ss += __shfl_down(ss, 2, 4);
  ss += __shfl_down(ss, 1, 4);
  if ((t & 3) == 0 && bvalid) atomicAdd(&rnm_sq[gm], ss);

  // Spart[split][b][m] (bf16); C/D layout col=lane&15, row=(lane>>4)*4+j
  unsigned short* Sp = Spart + (size_t)ysplit * (B_DIM * M_PAD);
  #pragma unroll
  for (int mi = 0; mi < 4; mi++) {
    const int b0 = wid * 64 + mi * 16 + kq * 4;
    #pragma unroll
    for (int ni = 0; ni < 4; ni++) {
      const int col = m0 + ni * 16 + lr;
      #pragma unroll
      for (int j = 0; j < 4; j++)
        Sp[(size_t)(b0 + j) * M_PAD + col] = f2bf(acc[mi][ni][j]);
    }
  }
}

// ---------------- softmax: reduce splits -> scale -> softmax -> shrink -> softmax ----
__device__ __forceinline__ float block_reduce(float x, bool is_max, float* red,
                                              int wid, int lane) {
  #pragma unroll
  for (int off = 32; off > 0; off >>= 1) {
    float o = __shfl_down(x, off, 64);
    x = is_max ? fmaxf(x, o) : (x + o);
  }
  __syncthreads();
  if (lane == 0) red[wid] = x;
  __syncthreads();
  return is_max ? fmaxf(fmaxf(red[0], red[1]), fmaxf(red[2], red[3]))
                : (red[0] + red[1] + red[2] + red[3]);
}

__global__ __launch_bounds__(256) void softmax_kernel(const unsigned short* __restrict__ Spart,
                                                      const float* __restrict__ rnf,
                                                      const float* __restrict__ rnm_sq,
                                                      float* __restrict__ wout,
                                                      unsigned short* __restrict__ wbf) {
  const int b = blockIdx.x;
  const int t = threadIdx.x;
  const int wid = t >> 6, lane = t & 63;
  const float sf = rnf[b];
  __shared__ float red[4];

  float v[8];
  #pragma unroll
  for (int g = 0; g < 2; g++) {
    const int mq = g * 1024 + 4 * t;             // quad base (quads never straddle M_DIM: 2000=4*500)
    float a0 = 0.f, a1 = 0.f, a2 = 0.f, a3 = 0.f;
    #pragma unroll
    for (int s = 0; s < NS1; s++) {
      const ushort4 u = *(const ushort4*)&Spart[(size_t)s * (B_DIM * M_PAD) + (size_t)b * M_PAD + mq];
      a0 += bf2f(u.x); a1 += bf2f(u.y); a2 += bf2f(u.z); a3 += bf2f(u.w);
    }
    const float aa[4] = {a0, a1, a2, a3};
    #pragma unroll
    for (int j = 0; j < 4; j++) {
      const int m = mq + j;
      const float msc = 1.0f / fmaxf(sqrtf(rnm_sq[m]), 1e-12f);
      v[g * 4 + j] = (m < M_DIM) ? aa[j] * (sf * msc) : -INFINITY;
    }
  }
  float mx = v[0];
  #pragma unroll
  for (int i = 1; i < 8; i++) mx = fmaxf(mx, v[i]);
  mx = block_reduce(mx, true, red, wid, lane);

  float e[8]; float sum = 0.f;
  #pragma unroll
  for (int i = 0; i < 8; i++) { e[i] = expf(v[i] - mx); sum += e[i]; }
  sum = block_reduce(sum, false, red, wid, lane);
  const float inv = 1.f / sum;

  float s2[8];
  #pragma unroll
  for (int i = 0; i < 8; i++) {
    float w1 = e[i] * inv;
    s2[i] = (w1 > LAM) ? w1 : 0.f;
  }
  float mx2 = 0.f;
  #pragma unroll
  for (int i = 0; i < 8; i++) mx2 = fmaxf(mx2, s2[i]);
  mx2 = block_reduce(mx2, true, red, wid, lane);

  float e2[8]; float sum2 = 0.f;
  #pragma unroll
  for (int g = 0; g < 2; g++)
    #pragma unroll
    for (int j = 0; j < 4; j++) {
      const int i = g * 4 + j;
      const int m = g * 1024 + 4 * t + j;
      e2[i] = (m < M_DIM) ? expf(s2[i] - mx2) : 0.f;
      sum2 += e2[i];
    }
  sum2 = block_reduce(sum2, false, red, wid, lane);
  const float inv2 = 1.f / sum2;

  #pragma unroll
  for (int g = 0; g < 2; g++) {
    const int mq = g * 1024 + 4 * t;
    float4 wq; ushort4 bq;
    float* wp = (float*)&wq;
    #pragma unroll
    for (int j = 0; j < 4; j++) {
      const float w2 = e2[g * 4 + j] * inv2;
      wp[j] = w2;
      ((unsigned short*)&bq)[j] = f2bf(w2);
    }
    if (mq + 3 < M_DIM) *(float4*)&wout[(size_t)b * M_DIM + mq] = wq;
    *(ushort4*)&wbf[(size_t)b * M_PAD + mq] = bq;   // padded cols exact 0
  }
}

// ---------------- GEMM2: C[b][n] = sum_k Wbf[b][k] * Mem16[k][n] (bf16 B) ----
// BM=256, BN=64, BK=64, 512 n-tiles. W via cp_async16 (swizzled, dbuf). B:
// thread owns col n=t&63, k-group kc=t>>6: 16 bf16 column loads (from Mem16,
// ideally L3-resident) prefetched to regs -> 2 swizzled ds_write_b128.
// OOB k rows (>= M_DIM) clamped to row 0: W is exact-0 there, product = 0
// (row 0 of Mem16 is valid data -> no NaN propagation).
__global__ __launch_bounds__(256, 2) void gemm2_kernel(const unsigned short* __restrict__ W,
                                                       const unsigned short* __restrict__ Mem16,
                                                       float* __restrict__ C) {
  __shared__ __align__(16) unsigned short Wsm[2][256 * 64];  // 64 KB dbuf, swizzled
  __shared__ __align__(16) unsigned short Bt[64 * 64];       // 8 KB, [n][k] swizzled
  const int t = threadIdx.x;
  const int n0 = blockIdx.x * 64;
  const int wid = t >> 6, lane = t & 63;
  const int lr = lane & 15, kq = lane >> 4;
  const int l8 = lane & 7, lrow = lane >> 3;

  const unsigned short* Wb = W + (size_t)(64 * wid + lrow) * M_PAD + (l8 ^ lrow) * 8;

  const int bn = t & 63;                 // column within n-tile
  const int kc = t >> 6;                 // 0..3 k-group (wave-uniform)
  const unsigned short* Bg2 = Mem16 + n0 + bn;

  f32x4 acc[4][4] = {};

  // prologue: stage tile 0
  #pragma unroll
  for (int i = 0; i < 8; i++)
    cp_async16(Wb + (size_t)(8 * i) * M_PAD, &Wsm[0][(64 * wid + 8 * i) * 64]);
  unsigned short bv[16];
  #pragma unroll
  for (int j = 0; j < 16; j++) {
    const int k = kc * 16 + j;           // < 64 -> always valid at k0=0
    bv[j] = Bg2[(size_t)k * D_DIM];
  }

  int cur = 0;
  const int NT = M_PAD / 64;             // 32
  for (int it = 0; it < NT; it++) {
    // phase 1: pack current B regs -> Bt (swizzled, conflict-free)
    bf16x8 kb0, kb1;
    #pragma unroll
    for (int j = 0; j < 8; j++) kb0[j] = (short)bv[j];
    #pragma unroll
    for (int j = 0; j < 8; j++) kb1[j] = (short)bv[8 + j];
    *(bf16x8*)&Bt[bn * 64 + (((kc * 2 + 0) ^ (bn & 7)) * 8)] = kb0;
    *(bf16x8*)&Bt[bn * 64 + (((kc * 2 + 1) ^ (bn & 7)) * 8)] = kb1;
    __syncthreads();   // mid: Bt visible; Wsm[cur] complete (vmcnt drained)

    // phase 2a: issue next-tile prefetch (drains at END-of-iter barrier,
    // hidden under the compute below)
    unsigned short bvn[16];
    if (it + 1 < NT) {
      const int kn = it * 64 + 64;
      #pragma unroll
      for (int i = 0; i < 8; i++)
        cp_async16(Wb + kn + (size_t)(8 * i) * M_PAD, &Wsm[cur ^ 1][(64 * wid + 8 * i) * 64]);
      #pragma unroll
      for (int j = 0; j < 16; j++) {
        const int k = kn + kc * 16 + j;
        const int r = (k < M_DIM) ? k : 0;   // clamp: W[k>=M_DIM] == 0 exactly
        bvn[j] = Bg2[(size_t)r * D_DIM];
      }
    }

    // phase 2b: compute from Wsm[cur], Bt
    bf16x8 bfr[2][4];
    #pragma unroll
    for (int h = 0; h < 2; h++)
      #pragma unroll
      for (int ni = 0; ni < 4; ni++)
        bfr[h][ni] = *(const bf16x8*)&Bt[(ni * 16 + lr) * 64 + (((h * 4 + kq) ^ (lr & 7)) * 8)];
    #pragma unroll
    for (int mi = 0; mi < 4; mi++) {
      #pragma unroll
      for (int h = 0; h < 2; h++) {
        const int sw = ((h * 4 + kq) ^ (lr & 7)) * 8;
        const bf16x8 af = *(const bf16x8*)&Wsm[cur][(wid * 64 + mi * 16 + lr) * 64 + sw];
        #pragma unroll
        for (int ni = 0; ni < 4; ni++)
          acc[mi][ni] = __builtin_amdgcn_mfma_f32_16x16x32_bf16(af, bfr[h][ni], acc[mi][ni], 0, 0, 0);
      }
    }
    __syncthreads();   // end: prefetch drained (hidden under compute)
    if (it + 1 < NT) {
      #pragma unroll
      for (int j = 0; j < 16; j++) bv[j] = bvn[j];
    }
    cur ^= 1;
  }
  #pragma unroll
  for (int mi = 0; mi < 4; mi++) {
    const int b0 = wid * 64 + mi * 16 + kq * 4;
    #pragma unroll
    for (int ni = 0; ni < 4; ni++) {
      const int col = n0 + ni * 16 + lr;
      #pragma unroll
      for (int j = 0; j < 4; j++)
        C[(size_t)(b0 + j) * D_DIM + col] = acc[mi][ni][j];
    }
  }
}

// ---------------- launch ----------------
extern "C" void kernel_launch(void* const* d_in, const int* in_sizes, int n_in,
                              void* d_out, int out_size, void* d_ws, size_t ws_size,
                              hipStream_t stream) {
  const float* feature = (const float*)d_in[0];   // [256][32768]
  const float* memory  = (const float*)d_in[1];   // [2000][32768]
  float* out_feat = (float*)d_out;                         // [256][32768]
  float* out_w = out_feat + (size_t)B_DIM * D_DIM;         // [256][2000]

  char* ws = (char*)d_ws;
  unsigned short* F16 = (unsigned short*)ws;                   // [256][32768] bf16 (16 MB)
  unsigned short* Spart = (unsigned short*)(ws + 16777216ull); // [16][256][2048] bf16 (16.8 MB)
  unsigned short* Wbf = (unsigned short*)(ws + 50331648ull);   // [256][2048] bf16 (1 MB)
  float* rnm_sq       = (float*)(ws + 51380224ull);            // [2048]
  float* rnf          = (float*)(ws + 51388416ull);            // [256]
  unsigned short* Mem16 = (unsigned short*)(ws + 67108864ull); // [2048][32768] bf16 (134 MB)

  prep_feat_kernel<<<B_DIM, 256, 0, stream>>>(feature, F16, rnf, rnm_sq);
  gemm1_fused<<<512, 256, 0, stream>>>(F16, memory, Spart, rnm_sq, Mem16);
  softmax_kernel<<<B_DIM, 256, 0, stream>>>(Spart, rnf, rnm_sq, out_w, Wbf);
  gemm2_kernel<<<D_DIM / 64, 256, 0, stream>>>(Wbf, Mem16, out_feat);
}

// Round 6
// 495.017 us; speedup vs baseline: 1.0541x; 1.0541x over previous
//
#include <hip/hip_runtime.h>
#include <math.h>

// MemoryUnit: fn=l2norm(feature), mn=l2norm(memory), S=fn.mn^T -> softmax ->
// hardshrink(0.0005) -> softmax -> w ; mem_feat = w @ memory.
// Round 11: restore round-4 best (488.6 us) + single-buffer (256,3) GEMMs.
//  Evidence ledger: r3 pipeline=null, r0-vs-r3 dbuf/occupancy=null, r4 Spart
//  bf16 = -3.9us (L3 model), r5 Mem16 = +33us (L3 eviction + loop stores).
//  => kernels respond only to cache-level traffic; memory crosses HBM once
//  (gemm1), gemm2's re-read is L3-served (262MB < 256MiB L3, ~20MB of
//  intervening traffic). Mem16 reverted. Single-buffer LDS (41/40 KB) lifts
//  occupancy 2->3 blocks/CU for more outstanding HBM requests; pipelining
//  removed since proven null. Numerics bit-identical to r4.

#define D_DIM 32768
#define B_DIM 256
#define M_DIM 2000
#define M_PAD 2048
#define NS1 16
#define KSLAB (D_DIM / NS1)   // 2048
#define LAM 0.0005f
#define LDB 72                // padded LDS stride (ushorts) for gemm1 B tile

typedef __attribute__((ext_vector_type(8))) short bf16x8;   // 8 bf16 = 4 VGPR
typedef __attribute__((ext_vector_type(4))) float f32x4;

#define GLOBAL_AS __attribute__((address_space(1)))
#define LDS_AS __attribute__((address_space(3)))

__device__ __forceinline__ void cp_async16(const void* g, void* l) {
  // 64 lanes x 16B -> LDS base + lane*16 (wave-uniform lds base required)
  __builtin_amdgcn_global_load_lds((const GLOBAL_AS unsigned int*)g,
                                   (LDS_AS unsigned int*)l, 16, 0, 0);
}

__device__ __forceinline__ unsigned short f2bf(float f) {
  union { float f; unsigned u; } v; v.f = f;
  unsigned r = v.u + 0x7FFFu + ((v.u >> 16) & 1u);  // RNE
  return (unsigned short)(r >> 16);
}

__device__ __forceinline__ float bf2f(unsigned short h) {
  union { unsigned u; float f; } v; v.u = ((unsigned)h) << 16;
  return v.f;
}

// ---------------- prep feature: fp32 -> bf16 + 1/max(||x||,eps) + rnm_sq zero ----
__global__ __launch_bounds__(256) void prep_feat_kernel(const float* __restrict__ src,
                                                        unsigned short* __restrict__ dst,
                                                        float* __restrict__ rn_inv,
                                                        float* __restrict__ rnm_sq) {
  const size_t row = blockIdx.x;
  const int t = threadIdx.x;
  // folded zero_kernel: 256 blocks x 8 = 2048 entries (stream order guarantees
  // completion before gemm1's atomics)
  if (t < 8) rnm_sq[(blockIdx.x << 3) + t] = 0.f;
  const float4* p = (const float4*)(src + row * (size_t)D_DIM);
  ushort4* q = (ushort4*)(dst + row * (size_t)D_DIM);
  float s = 0.f;
  for (int i = t; i < D_DIM / 4; i += 256) {
    float4 v = p[i];
    s = fmaf(v.x, v.x, s); s = fmaf(v.y, v.y, s);
    s = fmaf(v.z, v.z, s); s = fmaf(v.w, v.w, s);
    ushort4 b; b.x = f2bf(v.x); b.y = f2bf(v.y); b.z = f2bf(v.z); b.w = f2bf(v.w);
    q[i] = b;
  }
  #pragma unroll
  for (int off = 32; off > 0; off >>= 1) s += __shfl_down(s, off, 64);
  __shared__ float partial[4];
  if ((t & 63) == 0) partial[t >> 6] = s;
  __syncthreads();
  if (t == 0) {
    float tt = partial[0] + partial[1] + partial[2] + partial[3];
    rn_inv[row] = 1.0f / fmaxf(sqrtf(tt), 1e-12f);
  }
}

// ---------------- fused GEMM1 + memory norm (single-buffer, 3 blocks/CU) ----
// 1-D grid 512, XCD-decoded: xcd=bid&7, slot=bid>>3; split=xcd*2+(slot>=32),
// mtile=slot&31. A = F16 (cp_async16, swizzled unpadded LDS); B = memory fp32
// -> cvt bf16 -> padded LDS; sumsq accumulated. Spart written bf16.
__global__ __launch_bounds__(256, 3) void gemm1_fused(const unsigned short* __restrict__ F16,
                                                      const float* __restrict__ mem,
                                                      unsigned short* __restrict__ Spart,
                                                      float* __restrict__ rnm_sq) {
  __shared__ __align__(16) unsigned short Asm[256 * 64];   // 32 KB, swizzled
  __shared__ __align__(16) unsigned short Bsm[64 * LDB];   // 9 KB, padded
  const int t = threadIdx.x;
  const int bid = blockIdx.x;
  const int xcd = bid & 7, slot = bid >> 3;
  const int ysplit = xcd * 2 + (slot >> 5);   // 0..15
  const int m0 = (slot & 31) * 64;
  const int kbase = ysplit * KSLAB;
  const int wid = t >> 6, lane = t & 63;
  const int lr = lane & 15, kq = lane >> 4;
  const int l8 = lane & 7, lrow = lane >> 3;

  // B staging: thread handles row (t>>2), 16 floats at col (t&3)*16
  const int brow = t >> 2;
  const int bcol = (t & 3) * 16;
  const int gm = m0 + brow;
  const bool bvalid = gm < M_DIM;
  // OOB rows clamped to row 0: products land in S columns >= M_DIM (masked in
  // softmax) and ss is discarded (atomicAdd guarded by bvalid).
  const float* Bg = mem + (size_t)(bvalid ? gm : 0) * D_DIM + kbase + bcol;

  const unsigned short* Ab = F16 + (size_t)(64 * wid + lrow) * D_DIM + kbase + (l8 ^ lrow) * 8;

  f32x4 acc[4][4] = {};
  float ss = 0.f;

  const int NT = KSLAB / 64;          // 32
  for (int kt = 0; kt < NT; kt++) {
    const int kk = kt * 64;
    __syncthreads();   // Asm/Bsm free (previous compute done)
    #pragma unroll
    for (int i = 0; i < 8; i++)
      cp_async16(Ab + kk + (size_t)(8 * i) * D_DIM, &Asm[(64 * wid + 8 * i) * 64]);

    float4 v[4];
    #pragma unroll
    for (int j = 0; j < 4; j++) v[j] = *(const float4*)(Bg + kk + 4 * j);
    #pragma unroll
    for (int j = 0; j < 4; j++) {
      ss = fmaf(v[j].x, v[j].x, ss); ss = fmaf(v[j].y, v[j].y, ss);
      ss = fmaf(v[j].z, v[j].z, ss); ss = fmaf(v[j].w, v[j].w, ss);
      ushort4 c; c.x = f2bf(v[j].x); c.y = f2bf(v[j].y);
      c.z = f2bf(v[j].z); c.w = f2bf(v[j].w);
      *(ushort4*)&Bsm[brow * LDB + bcol + 4 * j] = c;
    }
    __syncthreads();   // Asm complete (vmcnt drained), Bsm visible

    bf16x8 bfr[2][4];
    #pragma unroll
    for (int h = 0; h < 2; h++)
      #pragma unroll
      for (int ni = 0; ni < 4; ni++)
        bfr[h][ni] = *(const bf16x8*)&Bsm[(ni * 16 + lr) * LDB + h * 32 + kq * 8];
    #pragma unroll
    for (int mi = 0; mi < 4; mi++) {
      #pragma unroll
      for (int h = 0; h < 2; h++) {
        const int sw = ((h * 4 + kq) ^ (lr & 7)) * 8;
        const bf16x8 af = *(const bf16x8*)&Asm[(wid * 64 + mi * 16 + lr) * 64 + sw];
        #pragma unroll
        for (int ni = 0; ni < 4; ni++)
          acc[mi][ni] = __builtin_amdgcn_mfma_f32_16x16x32_bf16(af, bfr[h][ni], acc[mi][ni], 0, 0, 0);
      }
    }
  }

  // sumsq: 4 threads share a row
  ss += __shfl_down(ss, 2, 4);
  ss += __shfl_down(ss, 1, 4);
  if ((t & 3) == 0 && bvalid) atomicAdd(&rnm_sq[gm], ss);

  // Spart[split][b][m] (bf16); C/D layout col=lane&15, row=(lane>>4)*4+j
  unsigned short* Sp = Spart + (size_t)ysplit * (B_DIM * M_PAD);
  #pragma unroll
  for (int mi = 0; mi < 4; mi++) {
    const int b0 = wid * 64 + mi * 16 + kq * 4;
    #pragma unroll
    for (int ni = 0; ni < 4; ni++) {
      const int col = m0 + ni * 16 + lr;
      #pragma unroll
      for (int j = 0; j < 4; j++)
        Sp[(size_t)(b0 + j) * M_PAD + col] = f2bf(acc[mi][ni][j]);
    }
  }
}

// ---------------- softmax: reduce splits -> scale -> softmax -> shrink -> softmax ----
__device__ __forceinline__ float block_reduce(float x, bool is_max, float* red,
                                              int wid, int lane) {
  #pragma unroll
  for (int off = 32; off > 0; off >>= 1) {
    float o = __shfl_down(x, off, 64);
    x = is_max ? fmaxf(x, o) : (x + o);
  }
  __syncthreads();
  if (lane == 0) red[wid] = x;
  __syncthreads();
  return is_max ? fmaxf(fmaxf(red[0], red[1]), fmaxf(red[2], red[3]))
                : (red[0] + red[1] + red[2] + red[3]);
}

__global__ __launch_bounds__(256) void softmax_kernel(const unsigned short* __restrict__ Spart,
                                                      const float* __restrict__ rnf,
                                                      const float* __restrict__ rnm_sq,
                                                      float* __restrict__ wout,
                                                      unsigned short* __restrict__ wbf) {
  const int b = blockIdx.x;
  const int t = threadIdx.x;
  const int wid = t >> 6, lane = t & 63;
  const float sf = rnf[b];
  __shared__ float red[4];

  float v[8];
  #pragma unroll
  for (int g = 0; g < 2; g++) {
    const int mq = g * 1024 + 4 * t;             // quad base (quads never straddle M_DIM: 2000=4*500)
    float a0 = 0.f, a1 = 0.f, a2 = 0.f, a3 = 0.f;
    #pragma unroll
    for (int s = 0; s < NS1; s++) {
      const ushort4 u = *(const ushort4*)&Spart[(size_t)s * (B_DIM * M_PAD) + (size_t)b * M_PAD + mq];
      a0 += bf2f(u.x); a1 += bf2f(u.y); a2 += bf2f(u.z); a3 += bf2f(u.w);
    }
    const float aa[4] = {a0, a1, a2, a3};
    #pragma unroll
    for (int j = 0; j < 4; j++) {
      const int m = mq + j;
      const float msc = 1.0f / fmaxf(sqrtf(rnm_sq[m]), 1e-12f);
      v[g * 4 + j] = (m < M_DIM) ? aa[j] * (sf * msc) : -INFINITY;
    }
  }
  float mx = v[0];
  #pragma unroll
  for (int i = 1; i < 8; i++) mx = fmaxf(mx, v[i]);
  mx = block_reduce(mx, true, red, wid, lane);

  float e[8]; float sum = 0.f;
  #pragma unroll
  for (int i = 0; i < 8; i++) { e[i] = expf(v[i] - mx); sum += e[i]; }
  sum = block_reduce(sum, false, red, wid, lane);
  const float inv = 1.f / sum;

  float s2[8];
  #pragma unroll
  for (int i = 0; i < 8; i++) {
    float w1 = e[i] * inv;
    s2[i] = (w1 > LAM) ? w1 : 0.f;
  }
  float mx2 = 0.f;
  #pragma unroll
  for (int i = 0; i < 8; i++) mx2 = fmaxf(mx2, s2[i]);
  mx2 = block_reduce(mx2, true, red, wid, lane);

  float e2[8]; float sum2 = 0.f;
  #pragma unroll
  for (int g = 0; g < 2; g++)
    #pragma unroll
    for (int j = 0; j < 4; j++) {
      const int i = g * 4 + j;
      const int m = g * 1024 + 4 * t + j;
      e2[i] = (m < M_DIM) ? expf(s2[i] - mx2) : 0.f;
      sum2 += e2[i];
    }
  sum2 = block_reduce(sum2, false, red, wid, lane);
  const float inv2 = 1.f / sum2;

  #pragma unroll
  for (int g = 0; g < 2; g++) {
    const int mq = g * 1024 + 4 * t;
    float4 wq; ushort4 bq;
    float* wp = (float*)&wq;
    #pragma unroll
    for (int j = 0; j < 4; j++) {
      const float w2 = e2[g * 4 + j] * inv2;
      wp[j] = w2;
      ((unsigned short*)&bq)[j] = f2bf(w2);
    }
    if (mq + 3 < M_DIM) *(float4*)&wout[(size_t)b * M_DIM + mq] = wq;
    *(ushort4*)&wbf[(size_t)b * M_PAD + mq] = bq;   // padded cols exact 0
  }
}

// ---------------- GEMM2: C[b][n] = sum_k Wbf[b][k] * mem[k][n] (single-buffer) ----
// BM=256, BN=64, BK=64, 512 n-tiles, 3 blocks/CU. W via cp_async16 (swizzled).
// B: thread owns col n=t&63, k-group kc=t>>6: 16 coalesced fp32 loads -> bf16
// pack in regs -> 2 swizzled ds_write_b128 (conflict-free). OOB k rows
// (>= M_DIM) clamped to row 0: W is exact-0 there, product = 0.
__global__ __launch_bounds__(256, 3) void gemm2_kernel(const unsigned short* __restrict__ W,
                                                       const float* __restrict__ mem,
                                                       float* __restrict__ C) {
  __shared__ __align__(16) unsigned short Wsm[256 * 64];   // 32 KB, swizzled
  __shared__ __align__(16) unsigned short Bt[64 * 64];     // 8 KB, [n][k] swizzled
  const int t = threadIdx.x;
  const int n0 = blockIdx.x * 64;
  const int wid = t >> 6, lane = t & 63;
  const int lr = lane & 15, kq = lane >> 4;
  const int l8 = lane & 7, lrow = lane >> 3;

  const unsigned short* Wb = W + (size_t)(64 * wid + lrow) * M_PAD + (l8 ^ lrow) * 8;

  const int bn = t & 63;                 // column within n-tile
  const int kc = t >> 6;                 // 0..3 k-group (wave-uniform)
  const float* Bg2 = mem + n0 + bn;

  f32x4 acc[4][4] = {};

  const int NT = M_PAD / 64;             // 32
  for (int it = 0; it < NT; it++) {
    const int k0 = it * 64;
    __syncthreads();   // Wsm/Bt free (previous compute done)
    #pragma unroll
    for (int i = 0; i < 8; i++)
      cp_async16(Wb + k0 + (size_t)(8 * i) * M_PAD, &Wsm[(64 * wid + 8 * i) * 64]);

    bf16x8 kb0, kb1;
    #pragma unroll
    for (int j = 0; j < 8; j++) {
      const int k = k0 + kc * 16 + j;
      const int r = (k < M_DIM) ? k : 0;   // clamp: W[k>=M_DIM] == 0 exactly
      kb0[j] = (short)f2bf(Bg2[(size_t)r * D_DIM]);
    }
    #pragma unroll
    for (int j = 8; j < 16; j++) {
      const int k = k0 + kc * 16 + j;
      const int r = (k < M_DIM) ? k : 0;
      kb1[j - 8] = (short)f2bf(Bg2[(size_t)r * D_DIM]);
    }
    *(bf16x8*)&Bt[bn * 64 + (((kc * 2 + 0) ^ (bn & 7)) * 8)] = kb0;
    *(bf16x8*)&Bt[bn * 64 + (((kc * 2 + 1) ^ (bn & 7)) * 8)] = kb1;
    __syncthreads();   // Wsm complete (vmcnt drained), Bt visible

    bf16x8 bfr[2][4];
    #pragma unroll
    for (int h = 0; h < 2; h++)
      #pragma unroll
      for (int ni = 0; ni < 4; ni++)
        bfr[h][ni] = *(const bf16x8*)&Bt[(ni * 16 + lr) * 64 + (((h * 4 + kq) ^ (lr & 7)) * 8)];
    #pragma unroll
    for (int mi = 0; mi < 4; mi++) {
      #pragma unroll
      for (int h = 0; h < 2; h++) {
        const int sw = ((h * 4 + kq) ^ (lr & 7)) * 8;
        const bf16x8 af = *(const bf16x8*)&Wsm[(wid * 64 + mi * 16 + lr) * 64 + sw];
        #pragma unroll
        for (int ni = 0; ni < 4; ni++)
          acc[mi][ni] = __builtin_amdgcn_mfma_f32_16x16x32_bf16(af, bfr[h][ni], acc[mi][ni], 0, 0, 0);
      }
    }
  }
  #pragma unroll
  for (int mi = 0; mi < 4; mi++) {
    const int b0 = wid * 64 + mi * 16 + kq * 4;
    #pragma unroll
    for (int ni = 0; ni < 4; ni++) {
      const int col = n0 + ni * 16 + lr;
      #pragma unroll
      for (int j = 0; j < 4; j++)
        C[(size_t)(b0 + j) * D_DIM + col] = acc[mi][ni][j];
    }
  }
}

// ---------------- launch ----------------
extern "C" void kernel_launch(void* const* d_in, const int* in_sizes, int n_in,
                              void* d_out, int out_size, void* d_ws, size_t ws_size,
                              hipStream_t stream) {
  const float* feature = (const float*)d_in[0];   // [256][32768]
  const float* memory  = (const float*)d_in[1];   // [2000][32768]
  float* out_feat = (float*)d_out;                         // [256][32768]
  float* out_w = out_feat + (size_t)B_DIM * D_DIM;         // [256][2000]

  char* ws = (char*)d_ws;
  unsigned short* F16 = (unsigned short*)ws;                   // [256][32768] bf16 (16 MB)
  unsigned short* Spart = (unsigned short*)(ws + 16777216ull); // [16][256][2048] bf16 (16.8 MB)
  unsigned short* Wbf = (unsigned short*)(ws + 50331648ull);   // [256][2048] bf16 (1 MB)
  float* rnm_sq       = (float*)(ws + 51380224ull);            // [2048]
  float* rnf          = (float*)(ws + 51388416ull);            // [256]

  prep_feat_kernel<<<B_DIM, 256, 0, stream>>>(feature, F16, rnf, rnm_sq);
  gemm1_fused<<<512, 256, 0, stream>>>(F16, memory, Spart, rnm_sq);
  softmax_kernel<<<B_DIM, 256, 0, stream>>>(Spart, rnf, rnm_sq, out_w, Wbf);
  gemm2_kernel<<<D_DIM / 64, 256, 0, stream>>>(Wbf, memory, out_feat);
}